// Round 9
// baseline (301.577 us; speedup 1.0000x reference)
//
#include <hip/hip_runtime.h>
#include <hip/hip_bf16.h>

typedef unsigned short ushort;
typedef unsigned int uint;
typedef unsigned long long u64;
typedef _Float16 f16;

#define NN 4096
#define PP 128
#define QQ 128
#define HD 256
#define KH 8
#define DD 64
#define KK 16384  // P*Q

typedef _Float16 f16x2 __attribute__((ext_vector_type(2)));
typedef _Float16 f16x4 __attribute__((ext_vector_type(4)));
typedef _Float16 f16x8 __attribute__((ext_vector_type(8)));
typedef __fp16 fp16x2 __attribute__((ext_vector_type(2)));  // cvt_pkrtz return type
typedef float f32x4 __attribute__((ext_vector_type(4)));

__device__ inline void async_lds16(const void* g, void* l) {
  __builtin_amdgcn_global_load_lds(
      (const __attribute__((address_space(1))) unsigned int*)g,
      (__attribute__((address_space(3))) unsigned int*)l, 16, 0, 0);
}

// ---------------------------------------------------------------------------
// K0: split W and Wt fp32 -> f16 hi + f16 lo; also zero the x accumulator
// (spare-thread fusion — saves a launch).
// ---------------------------------------------------------------------------
__global__ __launch_bounds__(256) void k0_split2(
    const float* __restrict__ W, const float* __restrict__ Wt,
    f16* __restrict__ hiW, f16* __restrict__ loW,
    f16* __restrict__ hiT, f16* __restrict__ loT, float* __restrict__ xz) {
  const int tid = blockIdx.x * 256 + threadIdx.x;
  const int i = tid * 4;
  if (tid < (NN * HD) / 4)
    *(float4*)&xz[i] = make_float4(0.f, 0.f, 0.f, 0.f);
  const float* src;
  f16 *hi, *lo;
  int off;
  if (i < HD * PP * QQ) { src = W; hi = hiW; lo = loW; off = i; }
  else { src = Wt; hi = hiT; lo = loT; off = i - HD * PP * QQ; }
  const float4 w = *(const float4*)&src[off];
  const float wf[4] = {w.x, w.y, w.z, w.w};
  f16x4 hv, lv;
#pragma unroll
  for (int j = 0; j < 4; ++j) {
    const f16 h = (f16)wf[j];
    hv[j] = h;
    lv[j] = (f16)(wf[j] - (float)h);
  }
  *(f16x4*)&hi[off] = hv;
  *(f16x4*)&lo[off] = lv;
}

// ---------------------------------------------------------------------------
// K1: bilinear via 2-pass fp16 MFMA. C[4096,256] = Z @ (Whi+Wlo)^T, Z rounded
// to fp16 on the fly. Block 256n x 256h (512 thr, 8 waves of 64n x 128h),
// BK=32, K-split 16 -> atomicAdd. 256 blocks @ 1/CU.
// Rationale: W logical reads = (NN/tile_n) * 16 MB; 256n tile halves the
// 512 MB LLC stream that bounded the 128n version.
// ---------------------------------------------------------------------------
__global__ __launch_bounds__(512, 2) void k1_bilinear(
    const float* __restrict__ xp, const float* __restrict__ xn,
    const f16* __restrict__ Whi, const f16* __restrict__ Wlo,
    float* __restrict__ xout) {
  __shared__ f16 whi[256 * 32];   // [h][k], XOR-swizzled 16B segs (16 KB)
  __shared__ f16 wlo[256 * 32];   // 16 KB
  __shared__ f16 zhi[256 * 40];   // [n][k] padded 32->40 (20 KB)
  __shared__ float xpt[8][256];   // [p][n] (8 KB)

  const int t = threadIdx.x;
  const int n0 = blockIdx.x * 256;
  const int kb = blockIdx.y * (KK / 16);  // 1024-wide K chunk
  const int pb = kb >> 7;                 // 8 p values per block

  for (int idx = t; idx < 2048; idx += 512) {
    const int p = idx & 7, n = idx >> 3;
    xpt[p][n] = xp[(size_t)(n0 + n) * PP + pb + p];
  }

  const int l = t & 63, w = t >> 6;
  const int wr = (w >> 1) * 64;   // 0,64,128,192
  const int wc = (w & 1) * 128;   // 0,128

  int aoff[4], boff[8];
#pragma unroll
  for (int i = 0; i < 4; ++i)
    aoff[i] = (wr + i * 16 + (l & 15)) * 40 + (l >> 4) * 8;
#pragma unroll
  for (int j = 0; j < 8; ++j) {
    const int hr = wc + j * 16 + (l & 15);
    boff[j] = hr * 32 + (((l >> 4) ^ ((hr ^ (hr >> 2)) & 3)) * 8);
  }

  // W staging: 256 rows x 4 segs = 1024 slots; 512 threads -> 2 row-groups
  const int shb = t >> 2, seg = t & 3;
  int gsw[2];
#pragma unroll
  for (int g = 0; g < 2; ++g) {
    const int r = shb + 128 * g;
    gsw[g] = seg ^ ((r ^ (r >> 2)) & 3);
  }

  const int zn = t >> 1, zko = (t & 1) * 16;

  f32x4 acc[4][8];
#pragma unroll
  for (int i = 0; i < 4; ++i)
#pragma unroll
    for (int j = 0; j < 8; ++j) acc[i][j] = (f32x4)0.f;

  for (int c = 0; c < 32; ++c) {
    const int kc = kb + c * 32;
    const int pl = c >> 2;             // local p index (0..7)
    const int q0 = (c & 3) * 32;       // q base within row

    __syncthreads();  // previous step's fragment reads done

#pragma unroll
    for (int g = 0; g < 2; ++g) {
      const int r = shb + 128 * g;
      async_lds16(Whi + (size_t)r * KK + kc + gsw[g] * 8, whi + r * 32 + seg * 8);
      async_lds16(Wlo + (size_t)r * KK + kc + gsw[g] * 8, wlo + r * 32 + seg * 8);
    }

    // form Z tile: 256 rows x 32 k; 16 elems/thread, fp16 round via pkrtz
    {
      const float xpv = xpt[pl][zn];
      const float* xr = xn + (size_t)(n0 + zn) * QQ + q0 + zko;
      float4 v0 = ((const float4*)xr)[0];
      float4 v1 = ((const float4*)xr)[1];
      float4 v2 = ((const float4*)xr)[2];
      float4 v3 = ((const float4*)xr)[3];
      float zz[16] = {v0.x, v0.y, v0.z, v0.w, v1.x, v1.y, v1.z, v1.w,
                      v2.x, v2.y, v2.z, v2.w, v3.x, v3.y, v3.z, v3.w};
      union { uint u[8]; uint4 q[2]; } ph;
#pragma unroll
      for (int j = 0; j < 8; ++j) {
        union { fp16x2 h; uint u; } cv;
        cv.h = __builtin_amdgcn_cvt_pkrtz(xpv * zz[2 * j], xpv * zz[2 * j + 1]);
        ph.u[j] = cv.u;
      }
      const int zo = zn * 40 + zko;
      *(uint4*)&zhi[zo] = ph.q[0];
      *(uint4*)&zhi[zo + 8] = ph.q[1];
    }

    __syncthreads();  // W (vmcnt drained) + Z visible

    f16x8 Ah[4];
#pragma unroll
    for (int i = 0; i < 4; ++i) Ah[i] = *(const f16x8*)&zhi[aoff[i]];
#pragma unroll
    for (int j = 0; j < 8; ++j) {
      const f16x8 Bh = *(const f16x8*)&whi[boff[j]];
      const f16x8 Bl = *(const f16x8*)&wlo[boff[j]];
#pragma unroll
      for (int i = 0; i < 4; ++i)
        acc[i][j] = __builtin_amdgcn_mfma_f32_16x16x32_f16(Ah[i], Bh, acc[i][j], 0, 0, 0);
#pragma unroll
      for (int i = 0; i < 4; ++i)
        acc[i][j] = __builtin_amdgcn_mfma_f32_16x16x32_f16(Ah[i], Bl, acc[i][j], 0, 0, 0);
    }
  }

#pragma unroll
  for (int i = 0; i < 4; ++i)
#pragma unroll
    for (int j = 0; j < 8; ++j) {
      const int row = n0 + wr + i * 16 + (l >> 4) * 4;
      const int col = wc + j * 16 + (l & 15);
#pragma unroll
      for (int r = 0; r < 4; ++r)
        atomicAdd(&xout[(size_t)(row + r) * HD + col], acc[i][j][r]);
    }
}

// ---------------------------------------------------------------------------
// K23: xt[k][n][d] = sum_h (x[n][h]+b[h]) * (Wthi+Wtlo)[k*64+d][h]
// 2-pass fp16 MFMA; bias+cvt fused in A-stage; u/v dot products fused in
// epilogue (cross-lane LDS reduction). Block 64n x 128cols (2 heads).
// ---------------------------------------------------------------------------
__global__ __launch_bounds__(256) void k23_xt(
    const float* __restrict__ x, const float* __restrict__ bb,
    const f16* __restrict__ Wthi, const f16* __restrict__ Wtlo,
    const float* __restrict__ av, float* __restrict__ xt,
    float* __restrict__ ssrc, float* __restrict__ sdst) {
  __shared__ f16 ah[64 * 40];
  __shared__ f16 bh[128 * 32];
  __shared__ f16 bl[128 * 32];
  __shared__ float red1[2][64][17];
  __shared__ float red2[2][64][17];
  const int t = threadIdx.x;
  const int n0 = blockIdx.x * 64;
  const int c0 = blockIdx.y * 128;
  const int l = t & 63, w = t >> 6;
  const int wn = (w & 1) * 32, wcc = (w >> 1) * 64;

  int aoff[2], boff[4];
#pragma unroll
  for (int i = 0; i < 2; ++i)
    aoff[i] = (wn + i * 16 + (l & 15)) * 40 + (l >> 4) * 8;
#pragma unroll
  for (int j = 0; j < 4; ++j) {
    const int hr = wcc + j * 16 + (l & 15);
    boff[j] = hr * 32 + (((l >> 4) ^ ((hr ^ (hr >> 2)) & 3)) * 8);
  }

  f32x4 acc[2][4];
#pragma unroll
  for (int i = 0; i < 2; ++i)
#pragma unroll
    for (int j = 0; j < 4; ++j) acc[i][j] = (f32x4)0.f;

  for (int kc = 0; kc < HD; kc += 32) {
    __syncthreads();
    {  // A stage: read x fp32 + bias, cvt f16, store 16B
      const int row = t >> 2, sg = t & 3;
      const float* xr = &x[(size_t)(n0 + row) * HD + kc + sg * 8];
      const float4 xa = ((const float4*)xr)[0];
      const float4 xb = ((const float4*)xr)[1];
      const float4 ba = *(const float4*)&bb[kc + sg * 8];
      const float4 bv = *(const float4*)&bb[kc + sg * 8 + 4];
      f16x8 o;
      o[0] = (f16)(xa.x + ba.x); o[1] = (f16)(xa.y + ba.y);
      o[2] = (f16)(xa.z + ba.z); o[3] = (f16)(xa.w + ba.w);
      o[4] = (f16)(xb.x + bv.x); o[5] = (f16)(xb.y + bv.y);
      o[6] = (f16)(xb.z + bv.z); o[7] = (f16)(xb.w + bv.w);
      *(f16x8*)&ah[row * 40 + sg * 8] = o;
    }
#pragma unroll
    for (int g = 0; g < 2; ++g) {  // B stage: 128 cols x 4 segs = 512 slots
      const int slot = g * 256 + t;
      const int col = slot >> 2, ps = slot & 3;
      const int ls = ps ^ ((col ^ (col >> 2)) & 3);
      *(uint4*)&bh[col * 32 + ps * 8] =
          *(const uint4*)&Wthi[(size_t)(c0 + col) * HD + kc + ls * 8];
      *(uint4*)&bl[col * 32 + ps * 8] =
          *(const uint4*)&Wtlo[(size_t)(c0 + col) * HD + kc + ls * 8];
    }
    __syncthreads();
    f16x8 Af[2];
#pragma unroll
    for (int i = 0; i < 2; ++i) Af[i] = *(const f16x8*)&ah[aoff[i]];
#pragma unroll
    for (int j = 0; j < 4; ++j) {
      const f16x8 Bh = *(const f16x8*)&bh[boff[j]];
      const f16x8 Bl = *(const f16x8*)&bl[boff[j]];
#pragma unroll
      for (int i = 0; i < 2; ++i)
        acc[i][j] = __builtin_amdgcn_mfma_f32_16x16x32_f16(Af[i], Bh, acc[i][j], 0, 0, 0);
#pragma unroll
      for (int i = 0; i < 2; ++i)
        acc[i][j] = __builtin_amdgcn_mfma_f32_16x16x32_f16(Af[i], Bl, acc[i][j], 0, 0, 0);
    }
  }

  // head handled by this wave: hh = w>>1; d of col j = j*16 + (l&15)
  const int hh = w >> 1;
  const int khead = (c0 >> 6) + hh;
  float a1v[4], a2v[4];
#pragma unroll
  for (int j = 0; j < 4; ++j) {
    const int d = j * 16 + (l & 15);
    a1v[j] = av[khead * (2 * DD) + d];
    a2v[j] = av[khead * (2 * DD) + DD + d];
  }

#pragma unroll
  for (int i = 0; i < 2; ++i)
#pragma unroll
    for (int r = 0; r < 4; ++r) {
      const int rowl = wn + i * 16 + (l >> 4) * 4 + r;
      float p1 = 0.f, p2 = 0.f;
#pragma unroll
      for (int j = 0; j < 4; ++j) {
        p1 += acc[i][j][r] * a1v[j];
        p2 += acc[i][j][r] * a2v[j];
      }
      red1[hh][rowl][l & 15] = p1;  // lanes with same l>>4 write same slot?
      red2[hh][rowl][l & 15] = p2;  // no: (rowl,l&15) unique per (i,r,lane)
    }

  // xt store
#pragma unroll
  for (int i = 0; i < 2; ++i)
#pragma unroll
    for (int j = 0; j < 4; ++j) {
      const int row = n0 + wn + i * 16 + (l >> 4) * 4;
      const int colg = c0 + wcc + j * 16 + (l & 15);
      const int k = colg >> 6, d = colg & 63;
#pragma unroll
      for (int r = 0; r < 4; ++r)
        xt[((size_t)(k * NN + row + r)) * DD + d] = acc[i][j][r];
    }

  __syncthreads();
  // reduce 16 partials per (head,row); 2 heads x 2 arrays x 64 rows = 256 slots
  {
    const int hh2 = t >> 7;          // head
    const int which = (t >> 6) & 1;  // 0 = ssrc, 1 = sdst
    const int row = t & 63;
    const float* rp = which ? &red2[hh2][row][0] : &red1[hh2][row][0];
    float s = 0.f;
#pragma unroll
    for (int g = 0; g < 16; ++g) s += rp[g];
    const int kk = (c0 >> 6) + hh2;
    if (which) sdst[kk * NN + n0 + row] = s;
    else ssrc[kk * NN + n0 + row] = s;
  }
}

// ---------------------------------------------------------------------------
// K4a: rank-and-scatter "sort" (exact total order via packed u64 keys)
// ---------------------------------------------------------------------------
__global__ __launch_bounds__(256) void k4_rank(
    const float* __restrict__ sdst, float* __restrict__ vsorted,
    int* __restrict__ perm) {
  __shared__ u64 kv[4096];
  const int k = blockIdx.y, t = threadIdx.x;
  for (int i = t; i < 4096; i += 256) {
    const uint u = __float_as_uint(sdst[k * NN + i]);
    const uint key = (u & 0x80000000u) ? ~u : (u | 0x80000000u);
    kv[i] = ((u64)key << 32) | (uint)i;
  }
  __syncthreads();
  const int m = blockIdx.x * 256 + t;
  const u64 my = kv[m];
  int cnt = 0;
#pragma unroll 16
  for (int j = 0; j < 4096; ++j) cnt += (kv[j] < my) ? 1 : 0;
  const uint key = (uint)(my >> 32);
  const uint u = (key & 0x80000000u) ? (key ^ 0x80000000u) : ~key;
  vsorted[k * NN + cnt] = __uint_as_float(u);
  perm[k * NN + cnt] = (int)(my & 0xFFFFFFFFu);
}

// ---------------------------------------------------------------------------
// K4b: per-(head,chunk) sums; LDS-staged gather + shared exp precompute.
// ---------------------------------------------------------------------------
__global__ __launch_bounds__(64) void k4b_chunksum(
    const float* __restrict__ vs, const int* __restrict__ perm,
    const float* __restrict__ xt, float* __restrict__ Chi, float* __restrict__ Clo) {
  __shared__ float rows[64][64];
  __shared__ float eh[64], el[64];
  const int c = blockIdx.x, k = blockIdx.y, t = threadIdx.x;
  const int base = k * NN + c * 64;
  {
    const float v = vs[base + t];
    eh[t] = __expf(v);
    el[t] = __expf(0.2f * v);
  }
#pragma unroll
  for (int r = 0; r < 16; ++r) {
    const int i = r * 4 + (t >> 4);
    const int p = perm[base + i];
    *(float4*)&rows[i][(t & 15) * 4] =
        *(const float4*)&xt[((size_t)(k * NN + p)) * DD + (t & 15) * 4];
  }
  __syncthreads();
  float shi = 0.f, slo = 0.f, whs = 0.f, wls = 0.f;
#pragma unroll 8
  for (int i = 0; i < 64; ++i) {
    const float val = rows[i][t];
    shi += eh[i] * val; slo += el[i] * val;
    whs += eh[i]; wls += el[i];
  }
  const int cb = (k * 64 + c) * 65;
  Chi[cb + t] = shi;
  Clo[cb + t] = slo;
  if (t == 0) { Chi[cb + 64] = whs; Clo[cb + 64] = wls; }
}

// ---------------------------------------------------------------------------
// K4c: scan chunk sums (LDS-staged): CloS = excl prefix, ChiS = incl suffix
// ---------------------------------------------------------------------------
__global__ __launch_bounds__(128) void k4c_scan(
    const float* __restrict__ Chi, const float* __restrict__ Clo,
    float* __restrict__ ChiS, float* __restrict__ CloS) {
  __shared__ float schi[64 * 65];
  __shared__ float sclo[64 * 65];
  const int k = blockIdx.x, t = threadIdx.x;
  for (int idx = t; idx < 4160; idx += 128) {
    schi[idx] = Chi[k * 4160 + idx];
    sclo[idx] = Clo[k * 4160 + idx];
  }
  __syncthreads();
  if (t >= 65) return;
  float run = 0.f;
  for (int c = 0; c < 64; ++c) {
    CloS[(k * 64 + c) * 65 + t] = run;
    run += sclo[c * 65 + t];
  }
  run = 0.f;
  for (int c = 63; c >= 0; --c) {
    run += schi[c * 65 + t];
    ChiS[(k * 64 + c) * 65 + t] = run;
  }
}

// ---------------------------------------------------------------------------
// K4d: expand to per-position prefix/suffix arrays (LDS-staged).
// ---------------------------------------------------------------------------
__global__ __launch_bounds__(64) void k4d_expand(
    const float* __restrict__ vs, const int* __restrict__ perm,
    const float* __restrict__ xt, const float* __restrict__ ChiS,
    const float* __restrict__ CloS, float* __restrict__ Phi,
    float* __restrict__ Plo) {
  __shared__ float rows[64][64];
  __shared__ float eh[64], el[64];
  const int c = blockIdx.x, k = blockIdx.y, t = threadIdx.x;
  const int base = k * NN + c * 64;
  const int cb = (k * 64 + c) * 65;
  {
    const float v = vs[base + t];
    eh[t] = __expf(v);
    el[t] = __expf(0.2f * v);
  }
#pragma unroll
  for (int r = 0; r < 16; ++r) {
    const int i = r * 4 + (t >> 4);
    const int p = perm[base + i];
    *(float4*)&rows[i][(t & 15) * 4] =
        *(const float4*)&xt[((size_t)(k * NN + p)) * DD + (t & 15) * 4];
  }
  __syncthreads();
  float run = CloS[cb + t];
  float wrun = CloS[cb + 64];
  for (int i = 0; i < 64; ++i) {
    const size_t rb = ((size_t)(k * 4097) + c * 64 + i) * 65;
    Plo[rb + t] = run;
    if (t == 0) Plo[rb + 64] = wrun;
    run += el[i] * rows[i][t];
    wrun += el[i];
  }
  if (c == 63) {
    const size_t rb = ((size_t)(k * 4097) + 4096) * 65;
    Plo[rb + t] = run;
    if (t == 0) Plo[rb + 64] = wrun;
  }
  run = (c < 63) ? ChiS[cb + 65 + t] : 0.f;
  wrun = (c < 63) ? ChiS[cb + 65 + 64] : 0.f;
  for (int i = 63; i >= 0; --i) {
    run += eh[i] * rows[i][t];
    wrun += eh[i];
    const size_t rb = ((size_t)(k * 4097) + c * 64 + i) * 65;
    Phi[rb + t] = run;
    if (t == 0) Phi[rb + 64] = wrun;
  }
  if (c == 63) {
    const size_t rb = ((size_t)(k * 4097) + 4096) * 65;
    Phi[rb + t] = 0.f;
    if (t == 0) Phi[rb + 64] = 0.f;
  }
}

// ---------------------------------------------------------------------------
// K6: per query: LDS binary search + combine + tanh. 4 queries/block.
// ---------------------------------------------------------------------------
__global__ __launch_bounds__(256) void k6_final(
    const float* __restrict__ ssrc, const float* __restrict__ vsorted,
    const float* __restrict__ Phi, const float* __restrict__ Plo,
    float* __restrict__ out) {
  __shared__ float vsh[4096];
  __shared__ int posSh[4];
  const int t = threadIdx.x;
  const int q0 = blockIdx.x * 4;
  const int k = q0 >> 12;
  for (int idx = t; idx < 1024; idx += 256)
    *(float4*)&vsh[idx * 4] = *(const float4*)&vsorted[k * NN + idx * 4];
  __syncthreads();
  if (t < 4) {
    const float thr = -ssrc[q0 + t];
    int lo = 0, hi = 4096;
    while (lo < hi) {
      const int mid = (lo + hi) >> 1;
      if (vsh[mid] < thr) lo = mid + 1; else hi = mid;
    }
    posSh[t] = lo;
  }
  __syncthreads();
  const int qi = q0 + (t >> 6);
  const int d = t & 63;
  const int n = qi & 4095;
  const float u = ssrc[qi];
  const size_t rb = ((size_t)(k * 4097) + posSh[t >> 6]) * 65;
  const float eu = __expf(u), el = __expf(0.2f * u);
  const float num = eu * Phi[rb + d] + el * Plo[rb + d];
  const float den = eu * Phi[rb + 64] + el * Plo[rb + 64];
  out[(size_t)n * (KH * DD) + k * DD + d] = tanhf(num / den);
}

extern "C" void kernel_launch(void* const* d_in, const int* in_sizes, int n_in,
                              void* d_out, int out_size, void* d_ws, size_t ws_size,
                              hipStream_t stream) {
  const float* xp = (const float*)d_in[0];
  const float* xn = (const float*)d_in[1];
  const float* W = (const float*)d_in[2];
  const float* bb = (const float*)d_in[3];
  const float* Wt = (const float*)d_in[4];
  const float* av = (const float*)d_in[5];
  float* out = (float*)d_out;

  char* ws = (char*)d_ws;
  // Phi/Plo overlay the W splits (temporally disjoint).
  f16* Whi    = (f16*)(ws);                       // 8 MB
  f16* Wlo    = (f16*)(ws + 8388608);             // 8 MB
  float* Phi  = (float*)(ws);                     // 8.52 MB (overlay)
  float* Plo  = (float*)(ws + 8522240);           // 8.52 MB (overlay)
  float* x    = (float*)(ws + 17044480);          // 4 MB
  float* xt   = (float*)(ws + 21238784);          // 8 MB
  f16* Wthi   = (f16*)(ws + 31724544);            // 256 KB
  f16* Wtlo   = (f16*)(ws + 31986688);            // 256 KB
  float* ssrc = (float*)(ws + 32248832);          // 128 KB
  float* sdst = (float*)(ws + 32379904);          // 128 KB
  float* vsort= (float*)(ws + 32510976);          // 128 KB
  int*   perm = (int*)  (ws + 32642048);          // 128 KB
  float* Chi  = (float*)(ws + 32773120);          // 133 KB
  float* Clo  = (float*)(ws + 32906240);          // 133 KB
  float* ChiS = (float*)(ws + 33039360);          // 133 KB
  float* CloS = (float*)(ws + 33172480);          // 133 KB -> ends ~33.3 MB

  k0_split2<<<(HD * PP * QQ + KH * DD * HD) / 1024, 256, 0, stream>>>(
      W, Wt, Whi, Wlo, Wthi, Wtlo, x);
  k1_bilinear<<<dim3(NN / 256, 16), 512, 0, stream>>>(xp, xn, Whi, Wlo, x);
  k23_xt<<<dim3(NN / 64, 4), 256, 0, stream>>>(x, bb, Wthi, Wtlo, av, xt, ssrc, sdst);
  k4_rank<<<dim3(16, KH), 256, 0, stream>>>(sdst, vsort, perm);
  k4b_chunksum<<<dim3(64, KH), 64, 0, stream>>>(vsort, perm, xt, Chi, Clo);
  k4c_scan<<<KH, 128, 0, stream>>>(Chi, Clo, ChiS, CloS);
  k4d_expand<<<dim3(64, KH), 64, 0, stream>>>(vsort, perm, xt, ChiS, CloS, Phi, Plo);
  k6_final<<<(KH * NN) / 4, 256, 0, stream>>>(ssrc, vsort, Phi, Plo, out);
}

// Round 10
// 294.073 us; speedup vs baseline: 1.0255x; 1.0255x over previous
//
#include <hip/hip_runtime.h>
#include <hip/hip_bf16.h>

typedef unsigned short ushort;
typedef unsigned int uint;
typedef unsigned long long u64;
typedef _Float16 f16;

#define NN 4096
#define PP 128
#define QQ 128
#define HD 256
#define KH 8
#define DD 64
#define KK 16384  // P*Q

typedef _Float16 f16x2 __attribute__((ext_vector_type(2)));
typedef _Float16 f16x4 __attribute__((ext_vector_type(4)));
typedef _Float16 f16x8 __attribute__((ext_vector_type(8)));
typedef __fp16 fp16x2 __attribute__((ext_vector_type(2)));  // cvt_pkrtz return type
typedef float f32x4 __attribute__((ext_vector_type(4)));

__device__ inline void async_lds16(const void* g, void* l) {
  __builtin_amdgcn_global_load_lds(
      (const __attribute__((address_space(1))) unsigned int*)g,
      (__attribute__((address_space(3))) unsigned int*)l, 16, 0, 0);
}

// ---------------------------------------------------------------------------
// K0: split W and Wt fp32 -> f16 hi + f16 lo; also zero the x accumulator.
// ---------------------------------------------------------------------------
__global__ __launch_bounds__(256) void k0_split2(
    const float* __restrict__ W, const float* __restrict__ Wt,
    f16* __restrict__ hiW, f16* __restrict__ loW,
    f16* __restrict__ hiT, f16* __restrict__ loT, float* __restrict__ xz) {
  const int tid = blockIdx.x * 256 + threadIdx.x;
  const int i = tid * 4;
  if (tid < (NN * HD) / 4)
    *(float4*)&xz[i] = make_float4(0.f, 0.f, 0.f, 0.f);
  const float* src;
  f16 *hi, *lo;
  int off;
  if (i < HD * PP * QQ) { src = W; hi = hiW; lo = loW; off = i; }
  else { src = Wt; hi = hiT; lo = loT; off = i - HD * PP * QQ; }
  const float4 w = *(const float4*)&src[off];
  const float wf[4] = {w.x, w.y, w.z, w.w};
  f16x4 hv, lv;
#pragma unroll
  for (int j = 0; j < 4; ++j) {
    const f16 h = (f16)wf[j];
    hv[j] = h;
    lv[j] = (f16)(wf[j] - (float)h);
  }
  *(f16x4*)&hi[off] = hv;
  *(f16x4*)&lo[off] = lv;
}

// ---------------------------------------------------------------------------
// K1: bilinear via 2-pass fp16 MFMA. Block 64n x 256h (256 thr, 4 waves of
// 64n x 64h), BK=32, K-split 16 -> atomicAdd. Grid (64,16)=1024 blocks.
// LDS = 37.9 KB -> 4 blocks/CU: four independent barrier groups per CU
// overlap the global_load_lds drain stall (R9 showed 1 block/CU exposes it).
// ---------------------------------------------------------------------------
__global__ __launch_bounds__(256, 4) void k1_bilinear(
    const float* __restrict__ xp, const float* __restrict__ xn,
    const f16* __restrict__ Whi, const f16* __restrict__ Wlo,
    float* __restrict__ xout) {
  __shared__ f16 whi[256 * 32];   // [h][k], XOR-swizzled 16B segs (16 KB)
  __shared__ f16 wlo[256 * 32];   // 16 KB
  __shared__ f16 zhi[64 * 40];    // [n][k] padded 32->40 (5 KB)

  const int t = threadIdx.x;
  const int n0 = blockIdx.x * 64;
  const int kb = blockIdx.y * (KK / 16);  // 1024-wide K chunk
  const int pb = kb >> 7;                 // 8 p values per block

  const int l = t & 63, w = t >> 6;
  const int wc = w * 64;          // h-quarter per wave

  int aoff[4], boff[4];
#pragma unroll
  for (int i = 0; i < 4; ++i)
    aoff[i] = (i * 16 + (l & 15)) * 40 + (l >> 4) * 8;
#pragma unroll
  for (int j = 0; j < 4; ++j) {
    const int hr = wc + j * 16 + (l & 15);
    boff[j] = hr * 32 + (((l >> 4) ^ ((hr ^ (hr >> 2)) & 3)) * 8);
  }

  // W staging: 256 rows x 4 segs; thread (shb,seg), 4 row-groups of 64
  const int shb = t >> 2, seg = t & 3;
  int gsw[4];
#pragma unroll
  for (int g = 0; g < 4; ++g) {
    const int r = shb + 64 * g;
    gsw[g] = seg ^ ((r ^ (r >> 2)) & 3);
  }

  // z-formation map: row zn (0..63), k-offset zko (0,8,16,24)
  const int zn = t >> 2, zko = (t & 3) * 8;
  // xp values for this thread's z-row, all 8 p of this K chunk, in regs
  float xpr[8];
#pragma unroll
  for (int pl = 0; pl < 8; ++pl)
    xpr[pl] = xp[(size_t)(n0 + zn) * PP + pb + pl];

  f32x4 acc[4][4];
#pragma unroll
  for (int i = 0; i < 4; ++i)
#pragma unroll
    for (int j = 0; j < 4; ++j) acc[i][j] = (f32x4)0.f;

  for (int c = 0; c < 32; ++c) {
    const int kc = kb + c * 32;
    const int pl = c >> 2;             // local p index (0..7)
    const int q0 = (c & 3) * 32;       // q base within row

    __syncthreads();  // previous step's fragment reads done

#pragma unroll
    for (int g = 0; g < 4; ++g) {
      const int r = shb + 64 * g;
      async_lds16(Whi + (size_t)r * KK + kc + gsw[g] * 8, whi + r * 32 + seg * 8);
      async_lds16(Wlo + (size_t)r * KK + kc + gsw[g] * 8, wlo + r * 32 + seg * 8);
    }

    // form Z tile: 64 rows x 32 k; 8 elems/thread, fp16 round via pkrtz
    {
      const float xpv = xpr[pl];
      const float* xr = xn + (size_t)(n0 + zn) * QQ + q0 + zko;
      const float4 v0 = ((const float4*)xr)[0];
      const float4 v1 = ((const float4*)xr)[1];
      union { uint u[4]; uint4 q; } ph;
      union { fp16x2 h; uint u; } cv;
      cv.h = __builtin_amdgcn_cvt_pkrtz(xpv * v0.x, xpv * v0.y); ph.u[0] = cv.u;
      cv.h = __builtin_amdgcn_cvt_pkrtz(xpv * v0.z, xpv * v0.w); ph.u[1] = cv.u;
      cv.h = __builtin_amdgcn_cvt_pkrtz(xpv * v1.x, xpv * v1.y); ph.u[2] = cv.u;
      cv.h = __builtin_amdgcn_cvt_pkrtz(xpv * v1.z, xpv * v1.w); ph.u[3] = cv.u;
      *(uint4*)&zhi[zn * 40 + zko] = ph.q;
    }

    __syncthreads();  // W (vmcnt drained) + Z visible

    f16x8 Ah[4];
#pragma unroll
    for (int i = 0; i < 4; ++i) Ah[i] = *(const f16x8*)&zhi[aoff[i]];
#pragma unroll
    for (int j = 0; j < 4; ++j) {
      const f16x8 Bh = *(const f16x8*)&whi[boff[j]];
      const f16x8 Bl = *(const f16x8*)&wlo[boff[j]];
#pragma unroll
      for (int i = 0; i < 4; ++i)
        acc[i][j] = __builtin_amdgcn_mfma_f32_16x16x32_f16(Ah[i], Bh, acc[i][j], 0, 0, 0);
#pragma unroll
      for (int i = 0; i < 4; ++i)
        acc[i][j] = __builtin_amdgcn_mfma_f32_16x16x32_f16(Ah[i], Bl, acc[i][j], 0, 0, 0);
    }
  }

#pragma unroll
  for (int i = 0; i < 4; ++i)
#pragma unroll
    for (int j = 0; j < 4; ++j) {
      const int row = n0 + i * 16 + (l >> 4) * 4;
      const int col = wc + j * 16 + (l & 15);
#pragma unroll
      for (int r = 0; r < 4; ++r)
        atomicAdd(&xout[(size_t)(row + r) * HD + col], acc[i][j][r]);
    }
}

// ---------------------------------------------------------------------------
// K23: xt[k][n][d] = sum_h (x[n][h]+b[h]) * (Wthi+Wtlo)[k*64+d][h]
// 2-pass fp16 MFMA; bias+cvt fused in A-stage; u/v dots fused in epilogue.
// ---------------------------------------------------------------------------
__global__ __launch_bounds__(256) void k23_xt(
    const float* __restrict__ x, const float* __restrict__ bb,
    const f16* __restrict__ Wthi, const f16* __restrict__ Wtlo,
    const float* __restrict__ av, float* __restrict__ xt,
    float* __restrict__ ssrc, float* __restrict__ sdst) {
  __shared__ f16 ah[64 * 40];
  __shared__ f16 bh[128 * 32];
  __shared__ f16 bl[128 * 32];
  __shared__ float red1[2][64][17];
  __shared__ float red2[2][64][17];
  const int t = threadIdx.x;
  const int n0 = blockIdx.x * 64;
  const int c0 = blockIdx.y * 128;
  const int l = t & 63, w = t >> 6;
  const int wn = (w & 1) * 32, wcc = (w >> 1) * 64;

  int aoff[2], boff[4];
#pragma unroll
  for (int i = 0; i < 2; ++i)
    aoff[i] = (wn + i * 16 + (l & 15)) * 40 + (l >> 4) * 8;
#pragma unroll
  for (int j = 0; j < 4; ++j) {
    const int hr = wcc + j * 16 + (l & 15);
    boff[j] = hr * 32 + (((l >> 4) ^ ((hr ^ (hr >> 2)) & 3)) * 8);
  }

  f32x4 acc[2][4];
#pragma unroll
  for (int i = 0; i < 2; ++i)
#pragma unroll
    for (int j = 0; j < 4; ++j) acc[i][j] = (f32x4)0.f;

  for (int kc = 0; kc < HD; kc += 32) {
    __syncthreads();
    {  // A stage: read x fp32 + bias, cvt f16, store 16B
      const int row = t >> 2, sg = t & 3;
      const float* xr = &x[(size_t)(n0 + row) * HD + kc + sg * 8];
      const float4 xa = ((const float4*)xr)[0];
      const float4 xb = ((const float4*)xr)[1];
      const float4 ba = *(const float4*)&bb[kc + sg * 8];
      const float4 bv = *(const float4*)&bb[kc + sg * 8 + 4];
      f16x8 o;
      o[0] = (f16)(xa.x + ba.x); o[1] = (f16)(xa.y + ba.y);
      o[2] = (f16)(xa.z + ba.z); o[3] = (f16)(xa.w + ba.w);
      o[4] = (f16)(xb.x + bv.x); o[5] = (f16)(xb.y + bv.y);
      o[6] = (f16)(xb.z + bv.z); o[7] = (f16)(xb.w + bv.w);
      *(f16x8*)&ah[row * 40 + sg * 8] = o;
    }
#pragma unroll
    for (int g = 0; g < 2; ++g) {  // B stage: 128 cols x 4 segs = 512 slots
      const int slot = g * 256 + t;
      const int col = slot >> 2, ps = slot & 3;
      const int ls = ps ^ ((col ^ (col >> 2)) & 3);
      *(uint4*)&bh[col * 32 + ps * 8] =
          *(const uint4*)&Wthi[(size_t)(c0 + col) * HD + kc + ls * 8];
      *(uint4*)&bl[col * 32 + ps * 8] =
          *(const uint4*)&Wtlo[(size_t)(c0 + col) * HD + kc + ls * 8];
    }
    __syncthreads();
    f16x8 Af[2];
#pragma unroll
    for (int i = 0; i < 2; ++i) Af[i] = *(const f16x8*)&ah[aoff[i]];
#pragma unroll
    for (int j = 0; j < 4; ++j) {
      const f16x8 Bh = *(const f16x8*)&bh[boff[j]];
      const f16x8 Bl = *(const f16x8*)&bl[boff[j]];
#pragma unroll
      for (int i = 0; i < 2; ++i)
        acc[i][j] = __builtin_amdgcn_mfma_f32_16x16x32_f16(Af[i], Bh, acc[i][j], 0, 0, 0);
#pragma unroll
      for (int i = 0; i < 2; ++i)
        acc[i][j] = __builtin_amdgcn_mfma_f32_16x16x32_f16(Af[i], Bl, acc[i][j], 0, 0, 0);
    }
  }

  const int hh = w >> 1;
  const int khead = (c0 >> 6) + hh;
  float a1v[4], a2v[4];
#pragma unroll
  for (int j = 0; j < 4; ++j) {
    const int d = j * 16 + (l & 15);
    a1v[j] = av[khead * (2 * DD) + d];
    a2v[j] = av[khead * (2 * DD) + DD + d];
  }

#pragma unroll
  for (int i = 0; i < 2; ++i)
#pragma unroll
    for (int r = 0; r < 4; ++r) {
      const int rowl = wn + i * 16 + (l >> 4) * 4 + r;
      float p1 = 0.f, p2 = 0.f;
#pragma unroll
      for (int j = 0; j < 4; ++j) {
        p1 += acc[i][j][r] * a1v[j];
        p2 += acc[i][j][r] * a2v[j];
      }
      red1[hh][rowl][l & 15] = p1;
      red2[hh][rowl][l & 15] = p2;
    }

#pragma unroll
  for (int i = 0; i < 2; ++i)
#pragma unroll
    for (int j = 0; j < 4; ++j) {
      const int row = n0 + wn + i * 16 + (l >> 4) * 4;
      const int colg = c0 + wcc + j * 16 + (l & 15);
      const int k = colg >> 6, d = colg & 63;
#pragma unroll
      for (int r = 0; r < 4; ++r)
        xt[((size_t)(k * NN + row + r)) * DD + d] = acc[i][j][r];
    }

  __syncthreads();
  {
    const int hh2 = t >> 7;
    const int which = (t >> 6) & 1;
    const int row = t & 63;
    const float* rp = which ? &red2[hh2][row][0] : &red1[hh2][row][0];
    float s = 0.f;
#pragma unroll
    for (int g = 0; g < 16; ++g) s += rp[g];
    const int kk = (c0 >> 6) + hh2;
    if (which) sdst[kk * NN + n0 + row] = s;
    else ssrc[kk * NN + n0 + row] = s;
  }
}

// ---------------------------------------------------------------------------
// K4a: rank-and-scatter "sort" (exact total order via packed u64 keys)
// ---------------------------------------------------------------------------
__global__ __launch_bounds__(256) void k4_rank(
    const float* __restrict__ sdst, float* __restrict__ vsorted,
    int* __restrict__ perm) {
  __shared__ u64 kv[4096];
  const int k = blockIdx.y, t = threadIdx.x;
  for (int i = t; i < 4096; i += 256) {
    const uint u = __float_as_uint(sdst[k * NN + i]);
    const uint key = (u & 0x80000000u) ? ~u : (u | 0x80000000u);
    kv[i] = ((u64)key << 32) | (uint)i;
  }
  __syncthreads();
  const int m = blockIdx.x * 256 + t;
  const u64 my = kv[m];
  int cnt = 0;
#pragma unroll 16
  for (int j = 0; j < 4096; ++j) cnt += (kv[j] < my) ? 1 : 0;
  const uint key = (uint)(my >> 32);
  const uint u = (key & 0x80000000u) ? (key ^ 0x80000000u) : ~key;
  vsorted[k * NN + cnt] = __uint_as_float(u);
  perm[k * NN + cnt] = (int)(my & 0xFFFFFFFFu);
}

// ---------------------------------------------------------------------------
// K4b: per-(head,chunk) sums; LDS-staged gather + shared exp precompute.
// ---------------------------------------------------------------------------
__global__ __launch_bounds__(64) void k4b_chunksum(
    const float* __restrict__ vs, const int* __restrict__ perm,
    const float* __restrict__ xt, float* __restrict__ Chi, float* __restrict__ Clo) {
  __shared__ float rows[64][64];
  __shared__ float eh[64], el[64];
  const int c = blockIdx.x, k = blockIdx.y, t = threadIdx.x;
  const int base = k * NN + c * 64;
  {
    const float v = vs[base + t];
    eh[t] = __expf(v);
    el[t] = __expf(0.2f * v);
  }
#pragma unroll
  for (int r = 0; r < 16; ++r) {
    const int i = r * 4 + (t >> 4);
    const int p = perm[base + i];
    *(float4*)&rows[i][(t & 15) * 4] =
        *(const float4*)&xt[((size_t)(k * NN + p)) * DD + (t & 15) * 4];
  }
  __syncthreads();
  float shi = 0.f, slo = 0.f, whs = 0.f, wls = 0.f;
#pragma unroll 8
  for (int i = 0; i < 64; ++i) {
    const float val = rows[i][t];
    shi += eh[i] * val; slo += el[i] * val;
    whs += eh[i]; wls += el[i];
  }
  const int cb = (k * 64 + c) * 65;
  Chi[cb + t] = shi;
  Clo[cb + t] = slo;
  if (t == 0) { Chi[cb + 64] = whs; Clo[cb + 64] = wls; }
}

// ---------------------------------------------------------------------------
// K4d: expand to per-position prefix/suffix arrays; chunk-scan (ex-k4c)
// computed in-block from LDS-staged chunk sums.
// ---------------------------------------------------------------------------
__global__ __launch_bounds__(64) void k4d_expand(
    const float* __restrict__ vs, const int* __restrict__ perm,
    const float* __restrict__ xt, const float* __restrict__ Chi,
    const float* __restrict__ Clo, float* __restrict__ Phi,
    float* __restrict__ Plo) {
  __shared__ float schi[64 * 65];
  __shared__ float sclo[64 * 65];
  __shared__ float rows[64][64];
  __shared__ float eh[64], el[64];
  const int c = blockIdx.x, k = blockIdx.y, t = threadIdx.x;
  const int base = k * NN + c * 64;
  for (int idx = t; idx < 4160; idx += 64) {
    schi[idx] = Chi[k * 4160 + idx];
    sclo[idx] = Clo[k * 4160 + idx];
  }
  {
    const float v = vs[base + t];
    eh[t] = __expf(v);
    el[t] = __expf(0.2f * v);
  }
#pragma unroll
  for (int r = 0; r < 16; ++r) {
    const int i = r * 4 + (t >> 4);
    const int p = perm[base + i];
    *(float4*)&rows[i][(t & 15) * 4] =
        *(const float4*)&xt[((size_t)(k * NN + p)) * DD + (t & 15) * 4];
  }
  __syncthreads();

  // in-block scan over chunk dim (broadcast LDS reads)
  float run = 0.f, wrun = 0.f;
  for (int cc = 0; cc < c; ++cc) {
    run += sclo[cc * 65 + t];
    wrun += sclo[cc * 65 + 64];
  }
  float runS = 0.f, wrunS = 0.f;
  for (int cc = c + 1; cc < 64; ++cc) {
    runS += schi[cc * 65 + t];
    wrunS += schi[cc * 65 + 64];
  }

  for (int i = 0; i < 64; ++i) {
    const size_t rb = ((size_t)(k * 4097) + c * 64 + i) * 65;
    Plo[rb + t] = run;
    if (t == 0) Plo[rb + 64] = wrun;
    run += el[i] * rows[i][t];
    wrun += el[i];
  }
  if (c == 63) {
    const size_t rb = ((size_t)(k * 4097) + 4096) * 65;
    Plo[rb + t] = run;
    if (t == 0) Plo[rb + 64] = wrun;
  }
  for (int i = 63; i >= 0; --i) {
    runS += eh[i] * rows[i][t];
    wrunS += eh[i];
    const size_t rb = ((size_t)(k * 4097) + c * 64 + i) * 65;
    Phi[rb + t] = runS;
    if (t == 0) Phi[rb + 64] = wrunS;
  }
  if (c == 63) {
    const size_t rb = ((size_t)(k * 4097) + 4096) * 65;
    Phi[rb + t] = 0.f;
    if (t == 0) Phi[rb + 64] = 0.f;
  }
}

// ---------------------------------------------------------------------------
// K6: per query: LDS binary search + combine + tanh. 4 queries/block.
// ---------------------------------------------------------------------------
__global__ __launch_bounds__(256) void k6_final(
    const float* __restrict__ ssrc, const float* __restrict__ vsorted,
    const float* __restrict__ Phi, const float* __restrict__ Plo,
    float* __restrict__ out) {
  __shared__ float vsh[4096];
  __shared__ int posSh[4];
  const int t = threadIdx.x;
  const int q0 = blockIdx.x * 4;
  const int k = q0 >> 12;
  for (int idx = t; idx < 1024; idx += 256)
    *(float4*)&vsh[idx * 4] = *(const float4*)&vsorted[k * NN + idx * 4];
  __syncthreads();
  if (t < 4) {
    const float thr = -ssrc[q0 + t];
    int lo = 0, hi = 4096;
    while (lo < hi) {
      const int mid = (lo + hi) >> 1;
      if (vsh[mid] < thr) lo = mid + 1; else hi = mid;
    }
    posSh[t] = lo;
  }
  __syncthreads();
  const int qi = q0 + (t >> 6);
  const int d = t & 63;
  const int n = qi & 4095;
  const float u = ssrc[qi];
  const size_t rb = ((size_t)(k * 4097) + posSh[t >> 6]) * 65;
  const float eu = __expf(u), el = __expf(0.2f * u);
  const float num = eu * Phi[rb + d] + el * Plo[rb + d];
  const float den = eu * Phi[rb + 64] + el * Plo[rb + 64];
  out[(size_t)n * (KH * DD) + k * DD + d] = tanhf(num / den);
}

extern "C" void kernel_launch(void* const* d_in, const int* in_sizes, int n_in,
                              void* d_out, int out_size, void* d_ws, size_t ws_size,
                              hipStream_t stream) {
  const float* xp = (const float*)d_in[0];
  const float* xn = (const float*)d_in[1];
  const float* W = (const float*)d_in[2];
  const float* bb = (const float*)d_in[3];
  const float* Wt = (const float*)d_in[4];
  const float* av = (const float*)d_in[5];
  float* out = (float*)d_out;

  char* ws = (char*)d_ws;
  // Phi/Plo overlay the W splits (temporally disjoint).
  f16* Whi    = (f16*)(ws);                       // 8 MB
  f16* Wlo    = (f16*)(ws + 8388608);             // 8 MB
  float* Phi  = (float*)(ws);                     // 8.52 MB (overlay)
  float* Plo  = (float*)(ws + 8522240);           // 8.52 MB (overlay)
  float* x    = (float*)(ws + 17044480);          // 4 MB
  float* xt   = (float*)(ws + 21238784);          // 8 MB
  f16* Wthi   = (f16*)(ws + 31724544);            // 256 KB
  f16* Wtlo   = (f16*)(ws + 31986688);            // 256 KB
  float* ssrc = (float*)(ws + 32248832);          // 128 KB
  float* sdst = (float*)(ws + 32379904);          // 128 KB
  float* vsort= (float*)(ws + 32510976);          // 128 KB
  int*   perm = (int*)  (ws + 32642048);          // 128 KB
  float* Chi  = (float*)(ws + 32773120);          // 133 KB
  float* Clo  = (float*)(ws + 32906240);          // 133 KB -> ends ~33.0 MB

  k0_split2<<<(HD * PP * QQ + KH * DD * HD) / 1024, 256, 0, stream>>>(
      W, Wt, Whi, Wlo, Wthi, Wtlo, x);
  k1_bilinear<<<dim3(NN / 64, 16), 256, 0, stream>>>(xp, xn, Whi, Wlo, x);
  k23_xt<<<dim3(NN / 64, 4), 256, 0, stream>>>(x, bb, Wthi, Wtlo, av, xt, ssrc, sdst);
  k4_rank<<<dim3(16, KH), 256, 0, stream>>>(sdst, vsort, perm);
  k4b_chunksum<<<dim3(64, KH), 64, 0, stream>>>(vsort, perm, xt, Chi, Clo);
  k4d_expand<<<dim3(64, KH), 64, 0, stream>>>(vsort, perm, xt, Chi, Clo, Phi, Plo);
  k6_final<<<(KH * NN) / 4, 256, 0, stream>>>(ssrc, vsort, Phi, Plo, out);
}

// Round 11
// 280.176 us; speedup vs baseline: 1.0764x; 1.0496x over previous
//
#include <hip/hip_runtime.h>
#include <hip/hip_bf16.h>

typedef unsigned short ushort;
typedef unsigned int uint;
typedef unsigned long long u64;
typedef _Float16 f16;

#define NN 4096
#define PP 128
#define QQ 128
#define HD 256
#define KH 8
#define DD 64
#define KK 16384  // P*Q

typedef _Float16 f16x2 __attribute__((ext_vector_type(2)));
typedef _Float16 f16x4 __attribute__((ext_vector_type(4)));
typedef _Float16 f16x8 __attribute__((ext_vector_type(8)));
typedef __fp16 fp16x2 __attribute__((ext_vector_type(2)));  // cvt_pkrtz return type
typedef float f32x4 __attribute__((ext_vector_type(4)));

__device__ inline void async_lds16(const void* g, void* l) {
  __builtin_amdgcn_global_load_lds(
      (const __attribute__((address_space(1))) unsigned int*)g,
      (__attribute__((address_space(3))) unsigned int*)l, 16, 0, 0);
}

// ---------------------------------------------------------------------------
// K0: split W and Wt fp32 -> f16 hi + f16 lo; also zero the x accumulator.
// ---------------------------------------------------------------------------
__global__ __launch_bounds__(256) void k0_split2(
    const float* __restrict__ W, const float* __restrict__ Wt,
    f16* __restrict__ hiW, f16* __restrict__ loW,
    f16* __restrict__ hiT, f16* __restrict__ loT, float* __restrict__ xz) {
  const int tid = blockIdx.x * 256 + threadIdx.x;
  const int i = tid * 4;
  if (tid < (NN * HD) / 4)
    *(float4*)&xz[i] = make_float4(0.f, 0.f, 0.f, 0.f);
  const float* src;
  f16 *hi, *lo;
  int off;
  if (i < HD * PP * QQ) { src = W; hi = hiW; lo = loW; off = i; }
  else { src = Wt; hi = hiT; lo = loT; off = i - HD * PP * QQ; }
  const float4 w = *(const float4*)&src[off];
  const float wf[4] = {w.x, w.y, w.z, w.w};
  f16x4 hv, lv;
#pragma unroll
  for (int j = 0; j < 4; ++j) {
    const f16 h = (f16)wf[j];
    hv[j] = h;
    lv[j] = (f16)(wf[j] - (float)h);
  }
  *(f16x4*)&hi[off] = hv;
  *(f16x4*)&lo[off] = lv;
}

// ---------------------------------------------------------------------------
// K1: bilinear via 2-pass fp16 MFMA. Block 128n x 128h (256 thr, 4 waves of
// 64n x 64h), BK=32, K-split 16, h-split 2 -> grid (32,16,2) = 1024 blocks.
// LDS = 30 KB -> 4-5 blocks/CU. W logical traffic = 512 MB (R8 level) with
// R10-level cross-block overlap — the two best axes combined.
// ---------------------------------------------------------------------------
__global__ __launch_bounds__(256, 4) void k1_bilinear(
    const float* __restrict__ xp, const float* __restrict__ xn,
    const f16* __restrict__ Whi, const f16* __restrict__ Wlo,
    float* __restrict__ xout) {
  __shared__ f16 whi[128 * 32];   // [h][k], XOR-swizzled 16B segs (8 KB)
  __shared__ f16 wlo[128 * 32];   // 8 KB
  __shared__ f16 zhi[128 * 40];   // [n][k] padded 32->40 (10 KB)
  __shared__ float xpt[8][128];   // 4 KB

  const int t = threadIdx.x;
  const int n0 = blockIdx.x * 128;
  const int kb = blockIdx.y * (KK / 16);  // 1024-wide K chunk
  const int h0 = blockIdx.z * 128;
  const int pb = kb >> 7;                 // 8 p values per block

  for (int idx = t; idx < 1024; idx += 256) {
    const int p = idx & 7, n = idx >> 3;
    xpt[p][n] = xp[(size_t)(n0 + n) * PP + pb + p];
  }

  const int l = t & 63, w = t >> 6;
  const int wr = (w >> 1) * 64, wc = (w & 1) * 64;

  int aoff[4], boff[4];
#pragma unroll
  for (int i = 0; i < 4; ++i)
    aoff[i] = (wr + i * 16 + (l & 15)) * 40 + (l >> 4) * 8;
#pragma unroll
  for (int j = 0; j < 4; ++j) {
    const int hr = wc + j * 16 + (l & 15);
    boff[j] = hr * 32 + (((l >> 4) ^ ((hr ^ (hr >> 2)) & 3)) * 8);
  }

  // W staging: 128 rows x 4 segs = 512 slots; 256 thr -> 2 row-groups of 64
  const int shb = t >> 2, seg = t & 3;
  int gsw[2];
#pragma unroll
  for (int g = 0; g < 2; ++g) {
    const int r = shb + 64 * g;
    gsw[g] = seg ^ ((r ^ (r >> 2)) & 3);
  }

  const int zn = t >> 1, zko = (t & 1) * 16;

  f32x4 acc[4][4];
#pragma unroll
  for (int i = 0; i < 4; ++i)
#pragma unroll
    for (int j = 0; j < 4; ++j) acc[i][j] = (f32x4)0.f;

  for (int c = 0; c < 32; ++c) {
    const int kc = kb + c * 32;
    const int pl = c >> 2;             // local p index (0..7)
    const int q0 = (c & 3) * 32;       // q base within row

    __syncthreads();  // previous step's fragment reads done (covers xpt too)

#pragma unroll
    for (int g = 0; g < 2; ++g) {
      const int r = shb + 64 * g;
      async_lds16(Whi + (size_t)(h0 + r) * KK + kc + gsw[g] * 8,
                  whi + r * 32 + seg * 8);
      async_lds16(Wlo + (size_t)(h0 + r) * KK + kc + gsw[g] * 8,
                  wlo + r * 32 + seg * 8);
    }

    // form Z tile: 128 rows x 32 k; 16 elems/thread, fp16 round via pkrtz
    {
      const float xpv = xpt[pl][zn];
      const float* xr = xn + (size_t)(n0 + zn) * QQ + q0 + zko;
      const float4 v0 = ((const float4*)xr)[0];
      const float4 v1 = ((const float4*)xr)[1];
      const float4 v2 = ((const float4*)xr)[2];
      const float4 v3 = ((const float4*)xr)[3];
      float zz[16] = {v0.x, v0.y, v0.z, v0.w, v1.x, v1.y, v1.z, v1.w,
                      v2.x, v2.y, v2.z, v2.w, v3.x, v3.y, v3.z, v3.w};
      union { uint u[8]; uint4 q[2]; } ph;
#pragma unroll
      for (int j = 0; j < 8; ++j) {
        union { fp16x2 h; uint u; } cv;
        cv.h = __builtin_amdgcn_cvt_pkrtz(xpv * zz[2 * j], xpv * zz[2 * j + 1]);
        ph.u[j] = cv.u;
      }
      const int zo = zn * 40 + zko;
      *(uint4*)&zhi[zo] = ph.q[0];
      *(uint4*)&zhi[zo + 8] = ph.q[1];
    }

    __syncthreads();  // W (vmcnt drained) + Z visible

    f16x8 Ah[4];
#pragma unroll
    for (int i = 0; i < 4; ++i) Ah[i] = *(const f16x8*)&zhi[aoff[i]];
#pragma unroll
    for (int j = 0; j < 4; ++j) {
      const f16x8 Bh = *(const f16x8*)&whi[boff[j]];
      const f16x8 Bl = *(const f16x8*)&wlo[boff[j]];
#pragma unroll
      for (int i = 0; i < 4; ++i)
        acc[i][j] = __builtin_amdgcn_mfma_f32_16x16x32_f16(Ah[i], Bh, acc[i][j], 0, 0, 0);
#pragma unroll
      for (int i = 0; i < 4; ++i)
        acc[i][j] = __builtin_amdgcn_mfma_f32_16x16x32_f16(Ah[i], Bl, acc[i][j], 0, 0, 0);
    }
  }

#pragma unroll
  for (int i = 0; i < 4; ++i)
#pragma unroll
    for (int j = 0; j < 4; ++j) {
      const int row = n0 + wr + i * 16 + (l >> 4) * 4;
      const int col = h0 + wc + j * 16 + (l & 15);
#pragma unroll
      for (int r = 0; r < 4; ++r)
        atomicAdd(&xout[(size_t)(row + r) * HD + col], acc[i][j][r]);
    }
}

// ---------------------------------------------------------------------------
// K23: xt[k][n][d] = sum_h (x[n][h]+b[h]) * (Wthi+Wtlo)[k*64+d][h]
// 2-pass fp16 MFMA; bias+cvt fused in A-stage; u/v dots fused in epilogue.
// ---------------------------------------------------------------------------
__global__ __launch_bounds__(256) void k23_xt(
    const float* __restrict__ x, const float* __restrict__ bb,
    const f16* __restrict__ Wthi, const f16* __restrict__ Wtlo,
    const float* __restrict__ av, float* __restrict__ xt,
    float* __restrict__ ssrc, float* __restrict__ sdst) {
  __shared__ f16 ah[64 * 40];
  __shared__ f16 bh[128 * 32];
  __shared__ f16 bl[128 * 32];
  __shared__ float red1[2][64][17];
  __shared__ float red2[2][64][17];
  const int t = threadIdx.x;
  const int n0 = blockIdx.x * 64;
  const int c0 = blockIdx.y * 128;
  const int l = t & 63, w = t >> 6;
  const int wn = (w & 1) * 32, wcc = (w >> 1) * 64;

  int aoff[2], boff[4];
#pragma unroll
  for (int i = 0; i < 2; ++i)
    aoff[i] = (wn + i * 16 + (l & 15)) * 40 + (l >> 4) * 8;
#pragma unroll
  for (int j = 0; j < 4; ++j) {
    const int hr = wcc + j * 16 + (l & 15);
    boff[j] = hr * 32 + (((l >> 4) ^ ((hr ^ (hr >> 2)) & 3)) * 8);
  }

  f32x4 acc[2][4];
#pragma unroll
  for (int i = 0; i < 2; ++i)
#pragma unroll
    for (int j = 0; j < 4; ++j) acc[i][j] = (f32x4)0.f;

  for (int kc = 0; kc < HD; kc += 32) {
    __syncthreads();
    {  // A stage: read x fp32 + bias, cvt f16, store 16B
      const int row = t >> 2, sg = t & 3;
      const float* xr = &x[(size_t)(n0 + row) * HD + kc + sg * 8];
      const float4 xa = ((const float4*)xr)[0];
      const float4 xb = ((const float4*)xr)[1];
      const float4 ba = *(const float4*)&bb[kc + sg * 8];
      const float4 bv = *(const float4*)&bb[kc + sg * 8 + 4];
      f16x8 o;
      o[0] = (f16)(xa.x + ba.x); o[1] = (f16)(xa.y + ba.y);
      o[2] = (f16)(xa.z + ba.z); o[3] = (f16)(xa.w + ba.w);
      o[4] = (f16)(xb.x + bv.x); o[5] = (f16)(xb.y + bv.y);
      o[6] = (f16)(xb.z + bv.z); o[7] = (f16)(xb.w + bv.w);
      *(f16x8*)&ah[row * 40 + sg * 8] = o;
    }
#pragma unroll
    for (int g = 0; g < 2; ++g) {  // B stage: 128 cols x 4 segs = 512 slots
      const int slot = g * 256 + t;
      const int col = slot >> 2, ps = slot & 3;
      const int ls = ps ^ ((col ^ (col >> 2)) & 3);
      *(uint4*)&bh[col * 32 + ps * 8] =
          *(const uint4*)&Wthi[(size_t)(c0 + col) * HD + kc + ls * 8];
      *(uint4*)&bl[col * 32 + ps * 8] =
          *(const uint4*)&Wtlo[(size_t)(c0 + col) * HD + kc + ls * 8];
    }
    __syncthreads();
    f16x8 Af[2];
#pragma unroll
    for (int i = 0; i < 2; ++i) Af[i] = *(const f16x8*)&ah[aoff[i]];
#pragma unroll
    for (int j = 0; j < 4; ++j) {
      const f16x8 Bh = *(const f16x8*)&bh[boff[j]];
      const f16x8 Bl = *(const f16x8*)&bl[boff[j]];
#pragma unroll
      for (int i = 0; i < 2; ++i)
        acc[i][j] = __builtin_amdgcn_mfma_f32_16x16x32_f16(Af[i], Bh, acc[i][j], 0, 0, 0);
#pragma unroll
      for (int i = 0; i < 2; ++i)
        acc[i][j] = __builtin_amdgcn_mfma_f32_16x16x32_f16(Af[i], Bl, acc[i][j], 0, 0, 0);
    }
  }

  const int hh = w >> 1;
  const int khead = (c0 >> 6) + hh;
  float a1v[4], a2v[4];
#pragma unroll
  for (int j = 0; j < 4; ++j) {
    const int d = j * 16 + (l & 15);
    a1v[j] = av[khead * (2 * DD) + d];
    a2v[j] = av[khead * (2 * DD) + DD + d];
  }

#pragma unroll
  for (int i = 0; i < 2; ++i)
#pragma unroll
    for (int r = 0; r < 4; ++r) {
      const int rowl = wn + i * 16 + (l >> 4) * 4 + r;
      float p1 = 0.f, p2 = 0.f;
#pragma unroll
      for (int j = 0; j < 4; ++j) {
        p1 += acc[i][j][r] * a1v[j];
        p2 += acc[i][j][r] * a2v[j];
      }
      red1[hh][rowl][l & 15] = p1;
      red2[hh][rowl][l & 15] = p2;
    }

#pragma unroll
  for (int i = 0; i < 2; ++i)
#pragma unroll
    for (int j = 0; j < 4; ++j) {
      const int row = n0 + wn + i * 16 + (l >> 4) * 4;
      const int colg = c0 + wcc + j * 16 + (l & 15);
      const int k = colg >> 6, d = colg & 63;
#pragma unroll
      for (int r = 0; r < 4; ++r)
        xt[((size_t)(k * NN + row + r)) * DD + d] = acc[i][j][r];
    }

  __syncthreads();
  {
    const int hh2 = t >> 7;
    const int which = (t >> 6) & 1;
    const int row = t & 63;
    const float* rp = which ? &red2[hh2][row][0] : &red1[hh2][row][0];
    float s = 0.f;
#pragma unroll
    for (int g = 0; g < 16; ++g) s += rp[g];
    const int kk = (c0 >> 6) + hh2;
    if (which) sdst[kk * NN + n0 + row] = s;
    else ssrc[kk * NN + n0 + row] = s;
  }
}

// ---------------------------------------------------------------------------
// K4a: rank-and-scatter "sort" (exact total order via packed u64 keys)
// ---------------------------------------------------------------------------
__global__ __launch_bounds__(256) void k4_rank(
    const float* __restrict__ sdst, float* __restrict__ vsorted,
    int* __restrict__ perm) {
  __shared__ u64 kv[4096];
  const int k = blockIdx.y, t = threadIdx.x;
  for (int i = t; i < 4096; i += 256) {
    const uint u = __float_as_uint(sdst[k * NN + i]);
    const uint key = (u & 0x80000000u) ? ~u : (u | 0x80000000u);
    kv[i] = ((u64)key << 32) | (uint)i;
  }
  __syncthreads();
  const int m = blockIdx.x * 256 + t;
  const u64 my = kv[m];
  int cnt = 0;
#pragma unroll 16
  for (int j = 0; j < 4096; ++j) cnt += (kv[j] < my) ? 1 : 0;
  const uint key = (uint)(my >> 32);
  const uint u = (key & 0x80000000u) ? (key ^ 0x80000000u) : ~key;
  vsorted[k * NN + cnt] = __uint_as_float(u);
  perm[k * NN + cnt] = (int)(my & 0xFFFFFFFFu);
}

// ---------------------------------------------------------------------------
// K4b: per-(head,chunk) sums; LDS-staged gather + shared exp precompute.
// ---------------------------------------------------------------------------
__global__ __launch_bounds__(64) void k4b_chunksum(
    const float* __restrict__ vs, const int* __restrict__ perm,
    const float* __restrict__ xt, float* __restrict__ Chi, float* __restrict__ Clo) {
  __shared__ float rows[64][64];
  __shared__ float eh[64], el[64];
  const int c = blockIdx.x, k = blockIdx.y, t = threadIdx.x;
  const int base = k * NN + c * 64;
  {
    const float v = vs[base + t];
    eh[t] = __expf(v);
    el[t] = __expf(0.2f * v);
  }
#pragma unroll
  for (int r = 0; r < 16; ++r) {
    const int i = r * 4 + (t >> 4);
    const int p = perm[base + i];
    *(float4*)&rows[i][(t & 15) * 4] =
        *(const float4*)&xt[((size_t)(k * NN + p)) * DD + (t & 15) * 4];
  }
  __syncthreads();
  float shi = 0.f, slo = 0.f, whs = 0.f, wls = 0.f;
#pragma unroll 8
  for (int i = 0; i < 64; ++i) {
    const float val = rows[i][t];
    shi += eh[i] * val; slo += el[i] * val;
    whs += eh[i]; wls += el[i];
  }
  const int cb = (k * 64 + c) * 65;
  Chi[cb + t] = shi;
  Clo[cb + t] = slo;
  if (t == 0) { Chi[cb + 64] = whs; Clo[cb + 64] = wls; }
}

// ---------------------------------------------------------------------------
// K4d: expand to per-position prefix/suffix arrays; chunk-scan computed
// in-block from LDS-staged chunk sums.
// ---------------------------------------------------------------------------
__global__ __launch_bounds__(64) void k4d_expand(
    const float* __restrict__ vs, const int* __restrict__ perm,
    const float* __restrict__ xt, const float* __restrict__ Chi,
    const float* __restrict__ Clo, float* __restrict__ Phi,
    float* __restrict__ Plo) {
  __shared__ float schi[64 * 65];
  __shared__ float sclo[64 * 65];
  __shared__ float rows[64][64];
  __shared__ float eh[64], el[64];
  const int c = blockIdx.x, k = blockIdx.y, t = threadIdx.x;
  const int base = k * NN + c * 64;
  for (int idx = t; idx < 4160; idx += 64) {
    schi[idx] = Chi[k * 4160 + idx];
    sclo[idx] = Clo[k * 4160 + idx];
  }
  {
    const float v = vs[base + t];
    eh[t] = __expf(v);
    el[t] = __expf(0.2f * v);
  }
#pragma unroll
  for (int r = 0; r < 16; ++r) {
    const int i = r * 4 + (t >> 4);
    const int p = perm[base + i];
    *(float4*)&rows[i][(t & 15) * 4] =
        *(const float4*)&xt[((size_t)(k * NN + p)) * DD + (t & 15) * 4];
  }
  __syncthreads();

  float run = 0.f, wrun = 0.f;
  for (int cc = 0; cc < c; ++cc) {
    run += sclo[cc * 65 + t];
    wrun += sclo[cc * 65 + 64];
  }
  float runS = 0.f, wrunS = 0.f;
  for (int cc = c + 1; cc < 64; ++cc) {
    runS += schi[cc * 65 + t];
    wrunS += schi[cc * 65 + 64];
  }

  for (int i = 0; i < 64; ++i) {
    const size_t rb = ((size_t)(k * 4097) + c * 64 + i) * 65;
    Plo[rb + t] = run;
    if (t == 0) Plo[rb + 64] = wrun;
    run += el[i] * rows[i][t];
    wrun += el[i];
  }
  if (c == 63) {
    const size_t rb = ((size_t)(k * 4097) + 4096) * 65;
    Plo[rb + t] = run;
    if (t == 0) Plo[rb + 64] = wrun;
  }
  for (int i = 63; i >= 0; --i) {
    runS += eh[i] * rows[i][t];
    wrunS += eh[i];
    const size_t rb = ((size_t)(k * 4097) + c * 64 + i) * 65;
    Phi[rb + t] = runS;
    if (t == 0) Phi[rb + 64] = wrunS;
  }
  if (c == 63) {
    const size_t rb = ((size_t)(k * 4097) + 4096) * 65;
    Phi[rb + t] = 0.f;
    if (t == 0) Phi[rb + 64] = 0.f;
  }
}

// ---------------------------------------------------------------------------
// K6: per query: LDS binary search + combine + tanh. 16 queries/block
// (amortizes the vsh staging 4x vs the 4-query version).
// ---------------------------------------------------------------------------
__global__ __launch_bounds__(256) void k6_final(
    const float* __restrict__ ssrc, const float* __restrict__ vsorted,
    const float* __restrict__ Phi, const float* __restrict__ Plo,
    float* __restrict__ out) {
  __shared__ float vsh[4096];
  __shared__ int posSh[16];
  const int t = threadIdx.x;
  const int q0 = blockIdx.x * 16;
  const int k = q0 >> 12;
  for (int idx = t; idx < 1024; idx += 256)
    *(float4*)&vsh[idx * 4] = *(const float4*)&vsorted[k * NN + idx * 4];
  __syncthreads();
  if (t < 16) {
    const float thr = -ssrc[q0 + t];
    int lo = 0, hi = 4096;
    while (lo < hi) {
      const int mid = (lo + hi) >> 1;
      if (vsh[mid] < thr) lo = mid + 1; else hi = mid;
    }
    posSh[t] = lo;
  }
  __syncthreads();
  const int d = t & 63;
#pragma unroll
  for (int qq = 0; qq < 4; ++qq) {
    const int ql = qq * 4 + (t >> 6);
    const int qi = q0 + ql;
    const int n = qi & 4095;
    const float u = ssrc[qi];
    const size_t rb = ((size_t)(k * 4097) + posSh[ql]) * 65;
    const float eu = __expf(u), el = __expf(0.2f * u);
    const float num = eu * Phi[rb + d] + el * Plo[rb + d];
    const float den = eu * Phi[rb + 64] + el * Plo[rb + 64];
    out[(size_t)n * (KH * DD) + k * DD + d] = tanhf(num / den);
  }
}

extern "C" void kernel_launch(void* const* d_in, const int* in_sizes, int n_in,
                              void* d_out, int out_size, void* d_ws, size_t ws_size,
                              hipStream_t stream) {
  const float* xp = (const float*)d_in[0];
  const float* xn = (const float*)d_in[1];
  const float* W = (const float*)d_in[2];
  const float* bb = (const float*)d_in[3];
  const float* Wt = (const float*)d_in[4];
  const float* av = (const float*)d_in[5];
  float* out = (float*)d_out;

  char* ws = (char*)d_ws;
  // Phi/Plo overlay the W splits (temporally disjoint).
  f16* Whi    = (f16*)(ws);                       // 8 MB
  f16* Wlo    = (f16*)(ws + 8388608);             // 8 MB
  float* Phi  = (float*)(ws);                     // 8.52 MB (overlay)
  float* Plo  = (float*)(ws + 8522240);           // 8.52 MB (overlay)
  float* x    = (float*)(ws + 17044480);          // 4 MB
  float* xt   = (float*)(ws + 21238784);          // 8 MB
  f16* Wthi   = (f16*)(ws + 31724544);            // 256 KB
  f16* Wtlo   = (f16*)(ws + 31986688);            // 256 KB
  float* ssrc = (float*)(ws + 32248832);          // 128 KB
  float* sdst = (float*)(ws + 32379904);          // 128 KB
  float* vsort= (float*)(ws + 32510976);          // 128 KB
  int*   perm = (int*)  (ws + 32642048);          // 128 KB
  float* Chi  = (float*)(ws + 32773120);          // 133 KB
  float* Clo  = (float*)(ws + 32906240);          // 133 KB -> ends ~33.0 MB

  k0_split2<<<(HD * PP * QQ + KH * DD * HD) / 1024, 256, 0, stream>>>(
      W, Wt, Whi, Wlo, Wthi, Wtlo, x);
  k1_bilinear<<<dim3(NN / 128, 16, 2), 256, 0, stream>>>(xp, xn, Whi, Wlo, x);
  k23_xt<<<dim3(NN / 64, 4), 256, 0, stream>>>(x, bb, Wthi, Wtlo, av, xt, ssrc, sdst);
  k4_rank<<<dim3(16, KH), 256, 0, stream>>>(sdst, vsort, perm);
  k4b_chunksum<<<dim3(64, KH), 64, 0, stream>>>(vsort, perm, xt, Chi, Clo);
  k4d_expand<<<dim3(64, KH), 64, 0, stream>>>(vsort, perm, xt, Chi, Clo, Phi, Plo);
  k6_final<<<(KH * NN) / 16, 256, 0, stream>>>(ssrc, vsort, Phi, Plo, out);
}